// Round 6
// baseline (378.451 us; speedup 1.0000x reference)
//
#include <hip/hip_runtime.h>

#define N0        200000
#define N1        25000
#define N2        5000
#define FANOUT    16
#define IN_FEATS  500
#define NH        128
#define NC        47
#define K_PAD     512

typedef __attribute__((ext_vector_type(4))) float f32x4;
typedef __attribute__((ext_vector_type(8))) short bf16x8;
typedef __attribute__((ext_vector_type(2))) unsigned int uint2_;
typedef __attribute__((ext_vector_type(4))) unsigned int uint4_;

__device__ __forceinline__ unsigned short f2bf(float f) {
    unsigned int u = __builtin_bit_cast(unsigned int, f);
    u += 0x7fffu + ((u >> 16) & 1u);          // RNE
    return (unsigned short)(u >> 16);
}
__device__ __forceinline__ float bfhi(unsigned int u) {
    return __builtin_bit_cast(float, u & 0xffff0000u);
}
__device__ __forceinline__ float bflo(unsigned int u) {
    return __builtin_bit_cast(float, u << 16);
}

// ---------------------------------------------------------------------------
// k0: Wt[c][k] = bf16(W1[k][c]), zero-padded to K_PAD.
// ---------------------------------------------------------------------------
__global__ __launch_bounds__(256) void k0_transpose(
    const float* __restrict__ W1, unsigned short* __restrict__ Wt)
{
    __shared__ unsigned short sm[64][NH];
    const int t = threadIdx.x;
    const int kbase = blockIdx.x * 64;

    for (int r = t >> 7; r < 64; r += 2) {
        const int k = kbase + r;
        const int c = t & (NH - 1);
        sm[r][c] = f2bf(k < IN_FEATS ? W1[(size_t)k * NH + c] : 0.f);
    }
    __syncthreads();

    const int c  = t >> 1;
    const int ko = (t & 1) * 32;
    unsigned short* dst = Wt + (size_t)c * K_PAD + kbase + ko;
    #pragma unroll
    for (int i = 0; i < 32; i += 8) {
        bf16x8 v;
        #pragma unroll
        for (int e = 0; e < 8; ++e) v[e] = (short)sm[ko + i + e][c];
        *(bf16x8*)(dst + i) = v;
    }
}

// ---------------------------------------------------------------------------
// kA: dense GEMM H0 = features @ W1  (bf16 MFMA, f32 A converted in-reg).
// 256 thr / 4 waves, 64 rows per block (wave = 16 rows x 128 cols).
// No LDS, no barriers: A straight from global (coalesced 128B/row-chunk),
// B-fragments from L2-resident Wt.
// ---------------------------------------------------------------------------
__global__ __launch_bounds__(256) void kA_gemm(
    const float* __restrict__ features,       // [N0, IN_FEATS]
    const unsigned short* __restrict__ Wt,    // [NH, K_PAD] bf16
    unsigned short* __restrict__ H0)          // [N0, NH] bf16
{
    const int lane = threadIdx.x & 63;
    const int wv   = threadIdx.x >> 6;
    const int l15  = lane & 15;
    const int lq   = lane >> 4;               // 0..3
    const int rowbase = blockIdx.x * 64 + wv * 16;
    const float* rowp = features + (size_t)(rowbase + l15) * IN_FEATS;

    f32x4 acc[8];
    #pragma unroll
    for (int n = 0; n < 8; ++n) acc[n] = (f32x4){0.f,0.f,0.f,0.f};

    // main K loop: kk = 0..14 fully in-bounds (ke+7 <= 479 < 500)
    #pragma unroll 3
    for (int kk = 0; kk < 15; ++kk) {
        const int ke = kk * 32 + lq * 8;
        f32x4 x = *(const f32x4*)(rowp + ke);
        f32x4 y = *(const f32x4*)(rowp + ke + 4);
        bf16x8 a;
        a[0]=(short)f2bf(x.x); a[1]=(short)f2bf(x.y); a[2]=(short)f2bf(x.z); a[3]=(short)f2bf(x.w);
        a[4]=(short)f2bf(y.x); a[5]=(short)f2bf(y.y); a[6]=(short)f2bf(y.z); a[7]=(short)f2bf(y.w);
        #pragma unroll
        for (int nt = 0; nt < 8; ++nt) {
            bf16x8 b = *(const bf16x8*)(Wt + (size_t)(nt * 16 + l15) * K_PAD + ke);
            acc[nt] = __builtin_amdgcn_mfma_f32_16x16x32_bf16(a, b, acc[nt], 0, 0, 0);
        }
    }
    // tail kk = 15: ke in {480,488,496,504}; mask beyond 500
    {
        const int ke = 480 + lq * 8;
        float v[8] = {0.f,0.f,0.f,0.f,0.f,0.f,0.f,0.f};
        if (ke + 7 < IN_FEATS) {
            f32x4 x = *(const f32x4*)(rowp + ke);
            f32x4 y = *(const f32x4*)(rowp + ke + 4);
            v[0]=x.x; v[1]=x.y; v[2]=x.z; v[3]=x.w;
            v[4]=y.x; v[5]=y.y; v[6]=y.z; v[7]=y.w;
        } else if (ke < IN_FEATS) {
            f32x4 x = *(const f32x4*)(rowp + ke);
            v[0]=x.x; v[1]=x.y; v[2]=x.z; v[3]=x.w;
        }
        bf16x8 a;
        #pragma unroll
        for (int e = 0; e < 8; ++e) a[e] = (short)f2bf(v[e]);
        #pragma unroll
        for (int nt = 0; nt < 8; ++nt) {
            bf16x8 b = *(const bf16x8*)(Wt + (size_t)(nt * 16 + l15) * K_PAD + ke);
            acc[nt] = __builtin_amdgcn_mfma_f32_16x16x32_bf16(a, b, acc[nt], 0, 0, 0);
        }
    }

    // epilogue: H0[row][col] bf16; acc[nt][rr] -> row = lq*4+rr, col = nt*16+l15
    #pragma unroll
    for (int nt = 0; nt < 8; ++nt) {
        const int col = nt * 16 + l15;
        #pragma unroll
        for (int rr = 0; rr < 4; ++rr) {
            const int row = rowbase + lq * 4 + rr;
            H0[(size_t)row * NH + col] = f2bf(acc[nt][rr]);
        }
    }
}

// ---------------------------------------------------------------------------
// kB: h1cat[i] = [m + b1, relu(m + b1)],  m = mean_j H0[src0[i,j]].
// One wave per output row. Lane half handles even/odd neighbors (uint2 = 4
// bf16 per lane over 32 lanes); halves combined via shfl_xor(32).
// ---------------------------------------------------------------------------
__global__ __launch_bounds__(256) void kB_gather(
    const unsigned short* __restrict__ H0,    // [N0, NH] bf16
    const int*   __restrict__ src0,           // [N1, FANOUT]
    const float* __restrict__ b1,             // [NH]
    unsigned short* __restrict__ h1cat)       // [N1, 2*NH] bf16
{
    const int lane = threadIdx.x & 63;
    const int wv   = threadIdx.x >> 6;
    const int row  = blockIdx.x * 4 + wv;     // N1 = 25000 = 6250*4
    const int half = lane >> 5;               // 0: even neighbors, 1: odd
    const int c4   = (lane & 31) * 4;         // 4 cols per lane

    const int rb = row * FANOUT;
    float a0=0.f, a1=0.f, a2=0.f, a3=0.f;

    #pragma unroll
    for (int j = 0; j < FANOUT / 2; ++j) {
        const int nb = src0[rb + 2 * j + half];
        uint2_ v = *(const uint2_*)(H0 + (size_t)nb * NH + c4);
        a0 += bflo(v.x); a1 += bfhi(v.x);
        a2 += bflo(v.y); a3 += bfhi(v.y);
    }
    // combine even/odd halves (lane ^ 32)
    a0 += __shfl_xor(a0, 32);
    a1 += __shfl_xor(a1, 32);
    a2 += __shfl_xor(a2, 32);
    a3 += __shfl_xor(a3, 32);

    f32x4 bias = *(const f32x4*)(b1 + c4);
    const float h0 = a0 * 0.0625f + bias.x;
    const float h1 = a1 * 0.0625f + bias.y;
    const float h2 = a2 * 0.0625f + bias.z;
    const float h3 = a3 * 0.0625f + bias.w;

    unsigned short* dst = h1cat + (size_t)row * 256;
    if (half == 0) {           // h half: cols c4..c4+3
        uint2_ w;
        w.x = (unsigned int)f2bf(h0) | ((unsigned int)f2bf(h1) << 16);
        w.y = (unsigned int)f2bf(h2) | ((unsigned int)f2bf(h3) << 16);
        *(uint2_*)(dst + c4) = w;
    } else {                   // relu half: cols 128+c4..
        uint2_ w;
        w.x = (unsigned int)f2bf(h0 > 0.f ? h0 : 0.f) | ((unsigned int)f2bf(h1 > 0.f ? h1 : 0.f) << 16);
        w.y = (unsigned int)f2bf(h2 > 0.f ? h2 : 0.f) | ((unsigned int)f2bf(h3 > 0.f ? h3 : 0.f) << 16);
        *(uint2_*)(dst + NH + c4) = w;
    }
}

// ---------------------------------------------------------------------------
// k2: gather-mean over bf16 h1cat + f32 GEMM [8x256]@[256x47] + bias.
// ---------------------------------------------------------------------------
__global__ __launch_bounds__(256) void k2_fused(
    const unsigned short* __restrict__ h1cat, // [N1, 256] bf16
    const int*   __restrict__ src1,           // [N2, FANOUT]
    const float* __restrict__ W2,             // [256, NC]
    const float* __restrict__ b2,             // [NC]
    float*       __restrict__ out)            // [N2, NC]
{
    __shared__ float sm[8][256];

    const int tid = threadIdx.x;
    const int r   = tid >> 5;
    const int s   = tid & 31;
    const int row = blockIdx.x * 8 + r;

    float acc[8] = {0.f,0.f,0.f,0.f,0.f,0.f,0.f,0.f};
    #pragma unroll
    for (int j = 0; j < FANOUT; ++j) {
        const int nb = src1[row * FANOUT + j];
        uint4_ v = *(const uint4_*)(h1cat + (size_t)nb * 256 + s * 8);
        acc[0] += bflo(v.x); acc[1] += bfhi(v.x);
        acc[2] += bflo(v.y); acc[3] += bfhi(v.y);
        acc[4] += bflo(v.z); acc[5] += bfhi(v.z);
        acc[6] += bflo(v.w); acc[7] += bfhi(v.w);
    }
    #pragma unroll
    for (int e = 0; e < 8; ++e) sm[r][s * 8 + e] = acc[e] * 0.0625f;
    __syncthreads();

    const int c0 = s, c1 = s + 32;
    float o0 = b2[c0];
    float o1 = (c1 < NC) ? b2[c1] : 0.f;
    for (int k = 0; k < 256; k += 4) {
        f32x4 mv = *(const f32x4*)&sm[r][k];
        #pragma unroll
        for (int e = 0; e < 4; ++e) {
            const float* wrow = W2 + (size_t)(k + e) * NC;
            o0 += mv[e] * wrow[c0];
            if (c1 < NC) o1 += mv[e] * wrow[c1];
        }
    }
    out[(size_t)row * NC + c0] = o0;
    if (c1 < NC) out[(size_t)row * NC + c1] = o1;
}

extern "C" void kernel_launch(void* const* d_in, const int* in_sizes, int n_in,
                              void* d_out, int out_size, void* d_ws, size_t ws_size,
                              hipStream_t stream)
{
    const float* features = (const float*)d_in[0];
    const int*   src0     = (const int*)  d_in[1];
    const int*   src1     = (const int*)  d_in[2];
    const float* W1       = (const float*)d_in[3];
    const float* b1       = (const float*)d_in[4];
    const float* W2       = (const float*)d_in[5];
    const float* b2       = (const float*)d_in[6];
    float*       out      = (float*)d_out;

    unsigned short* Wt    = (unsigned short*)d_ws;        // [NH][K_PAD]  = 128 KB
    unsigned short* H0    = Wt + (size_t)NH * K_PAD;      // [N0][NH] bf16 = 51.2 MB
    unsigned short* h1cat = H0 + (size_t)N0 * NH;         // [N1][256] bf16 = 12.8 MB

    hipLaunchKernelGGL(k0_transpose, dim3(K_PAD / 64), dim3(256), 0, stream, W1, Wt);
    hipLaunchKernelGGL(kA_gemm,   dim3(N0 / 64), dim3(256), 0, stream, features, Wt, H0);
    hipLaunchKernelGGL(kB_gather, dim3(N1 / 4),  dim3(256), 0, stream, H0, src0, b1, h1cat);
    hipLaunchKernelGGL(k2_fused,  dim3(N2 / 8),  dim3(256), 0, stream, h1cat, src1, W2, b2, out);
}

// Round 7
// 315.629 us; speedup vs baseline: 1.1990x; 1.1990x over previous
//
#include <hip/hip_runtime.h>

#define N0        200000
#define N1        25000
#define N2        5000
#define FANOUT    16
#define IN_FEATS  500
#define NH        128
#define NC        47
#define K_PAD     512
#define ROWS_A    32          // rows per block in kA (32 KB LDS tile)

typedef __attribute__((ext_vector_type(4))) float f32x4;
typedef __attribute__((ext_vector_type(8))) short bf16x8;
typedef __attribute__((ext_vector_type(2))) unsigned int uint2_;
typedef __attribute__((ext_vector_type(4))) unsigned int uint4_;

__device__ __forceinline__ unsigned short f2bf(float f) {
    unsigned int u = __builtin_bit_cast(unsigned int, f);
    u += 0x7fffu + ((u >> 16) & 1u);          // RNE
    return (unsigned short)(u >> 16);
}
__device__ __forceinline__ float bfhi(unsigned int u) {
    return __builtin_bit_cast(float, u & 0xffff0000u);
}
__device__ __forceinline__ float bflo(unsigned int u) {
    return __builtin_bit_cast(float, u << 16);
}

// ---------------------------------------------------------------------------
// k0: Wt[c][k] = bf16(W1[k][c]), zero-padded to K_PAD.
// ---------------------------------------------------------------------------
__global__ __launch_bounds__(256) void k0_transpose(
    const float* __restrict__ W1, unsigned short* __restrict__ Wt)
{
    __shared__ unsigned short sm[64][NH];
    const int t = threadIdx.x;
    const int kbase = blockIdx.x * 64;

    for (int r = t >> 7; r < 64; r += 2) {
        const int k = kbase + r;
        const int c = t & (NH - 1);
        sm[r][c] = f2bf(k < IN_FEATS ? W1[(size_t)k * NH + c] : 0.f);
    }
    __syncthreads();

    const int c  = t >> 1;
    const int ko = (t & 1) * 32;
    unsigned short* dst = Wt + (size_t)c * K_PAD + kbase + ko;
    #pragma unroll
    for (int i = 0; i < 32; i += 8) {
        bf16x8 v;
        #pragma unroll
        for (int e = 0; e < 8; ++e) v[e] = (short)sm[ko + i + e][c];
        *(bf16x8*)(dst + i) = v;
    }
}

// ---------------------------------------------------------------------------
// kA: dense GEMM H0 = features @ W1 (bf16 MFMA).
// Per block: contiguous 32-row slab loaded FLAT+COALESCED (4KB/wave-instr,
// nontemporal), converted to bf16, ds_write into XOR-swizzled LDS tile;
// then MFMA with A from LDS, B from L2-resident Wt.
// 4 waves: wave w -> row-tile (w&1), cols (w>>1)*64..+63.
// ---------------------------------------------------------------------------
__global__ __launch_bounds__(256) void kA_gemm(
    const float* __restrict__ features,       // [N0, IN_FEATS]
    const unsigned short* __restrict__ Wt,    // [NH, K_PAD] bf16
    unsigned short* __restrict__ H0)          // [N0, NH] bf16
{
    __shared__ unsigned short A[ROWS_A * K_PAD];   // 32 KB, swizzled rows

    const int tid  = threadIdx.x;
    const int lane = tid & 63;
    const int wv   = tid >> 6;
    const int l15  = lane & 15;
    const int lq   = lane >> 4;               // 0..3
    const int rowbase = blockIdx.x * ROWS_A;

    // ---- Phase A: coalesced flat staging of 32x500 f32 -> bf16 LDS tile ----
    // slab = 16000 floats = 4000 f32x4 chunks; thread t takes e = t, t+256, ...
    const f32x4* slab = (const f32x4*)(features + (size_t)rowbase * IN_FEATS);
    #pragma unroll 4
    for (int e = tid; e < 4000; e += 256) {
        f32x4 v = __builtin_nontemporal_load(slab + e);
        const int row = e / 125;               // 125 chunks per row
        const int k4  = (e - row * 125) * 4;   // element offset in row
        uint2_ w;
        w.x = (unsigned int)f2bf(v.x) | ((unsigned int)f2bf(v.y) << 16);
        w.y = (unsigned int)f2bf(v.z) | ((unsigned int)f2bf(v.w) << 16);
        const int boff = row * 1024 + ((k4 * 2) ^ ((row & 7) << 4));
        *(uint2_*)((char*)A + boff) = w;
    }
    // zero-pad k in [500,512): 32 rows x 12 elems, 8B chunks
    if (tid < 96) {
        const int row = tid / 3;
        const int k4  = 500 + (tid % 3) * 4;
        uint2_ z = {0u, 0u};
        const int boff = row * 1024 + ((k4 * 2) ^ ((row & 7) << 4));
        *(uint2_*)((char*)A + boff) = z;
    }
    __syncthreads();

    // ---- Phase B: MFMA. wave -> 16 rows x 64 cols ----
    const int rt = wv & 1;                    // row-tile (0..1)
    const int ch = wv >> 1;                   // col half (0..1)

    f32x4 acc[4];
    #pragma unroll
    for (int n = 0; n < 4; ++n) acc[n] = (f32x4){0.f,0.f,0.f,0.f};

    const int arow = rt * 16 + l15;
    const int arow_base = arow * 1024;
    const int aswz = (arow & 7) << 4;

    #pragma unroll 4
    for (int kk = 0; kk < 16; ++kk) {
        const int ke = kk * 32 + lq * 8;
        bf16x8 a = *(const bf16x8*)((const char*)A + arow_base + ((ke * 2) ^ aswz));
        #pragma unroll
        for (int nt = 0; nt < 4; ++nt) {
            const int col = ch * 64 + nt * 16 + l15;
            bf16x8 b = *(const bf16x8*)(Wt + (size_t)col * K_PAD + ke);
            acc[nt] = __builtin_amdgcn_mfma_f32_16x16x32_bf16(a, b, acc[nt], 0, 0, 0);
        }
    }

    // ---- Epilogue: H0 bf16 ----
    #pragma unroll
    for (int nt = 0; nt < 4; ++nt) {
        const int col = ch * 64 + nt * 16 + l15;
        #pragma unroll
        for (int rr = 0; rr < 4; ++rr) {
            const int row = rowbase + rt * 16 + lq * 4 + rr;
            H0[(size_t)row * NH + col] = f2bf(acc[nt][rr]);
        }
    }
}

// ---------------------------------------------------------------------------
// kB: h1cat[i] = [m + b1, relu(m + b1)],  m = mean_j H0[src0[i,j]].
// One wave per output row; halves (even/odd neighbors) combined via shfl.
// ---------------------------------------------------------------------------
__global__ __launch_bounds__(256) void kB_gather(
    const unsigned short* __restrict__ H0,    // [N0, NH] bf16
    const int*   __restrict__ src0,           // [N1, FANOUT]
    const float* __restrict__ b1,             // [NH]
    unsigned short* __restrict__ h1cat)       // [N1, 2*NH] bf16
{
    const int lane = threadIdx.x & 63;
    const int wv   = threadIdx.x >> 6;
    const int row  = blockIdx.x * 4 + wv;     // N1 = 6250*4
    const int half = lane >> 5;               // 0: even neighbors, 1: odd
    const int c4   = (lane & 31) * 4;         // 4 cols per lane

    const int rb = row * FANOUT;
    float a0=0.f, a1=0.f, a2=0.f, a3=0.f;

    #pragma unroll
    for (int j = 0; j < FANOUT / 2; ++j) {
        const int nb = src0[rb + 2 * j + half];
        uint2_ v = *(const uint2_*)(H0 + (size_t)nb * NH + c4);
        a0 += bflo(v.x); a1 += bfhi(v.x);
        a2 += bflo(v.y); a3 += bfhi(v.y);
    }
    a0 += __shfl_xor(a0, 32);
    a1 += __shfl_xor(a1, 32);
    a2 += __shfl_xor(a2, 32);
    a3 += __shfl_xor(a3, 32);

    f32x4 bias = *(const f32x4*)(b1 + c4);
    const float h0 = a0 * 0.0625f + bias.x;
    const float h1 = a1 * 0.0625f + bias.y;
    const float h2 = a2 * 0.0625f + bias.z;
    const float h3 = a3 * 0.0625f + bias.w;

    unsigned short* dst = h1cat + (size_t)row * 256;
    if (half == 0) {
        uint2_ w;
        w.x = (unsigned int)f2bf(h0) | ((unsigned int)f2bf(h1) << 16);
        w.y = (unsigned int)f2bf(h2) | ((unsigned int)f2bf(h3) << 16);
        *(uint2_*)(dst + c4) = w;
    } else {
        uint2_ w;
        w.x = (unsigned int)f2bf(h0 > 0.f ? h0 : 0.f) | ((unsigned int)f2bf(h1 > 0.f ? h1 : 0.f) << 16);
        w.y = (unsigned int)f2bf(h2 > 0.f ? h2 : 0.f) | ((unsigned int)f2bf(h3 > 0.f ? h3 : 0.f) << 16);
        *(uint2_*)(dst + NH + c4) = w;
    }
}

// ---------------------------------------------------------------------------
// k2: gather-mean over bf16 h1cat + f32 GEMM [8x256]@[256x47] + bias.
// ---------------------------------------------------------------------------
__global__ __launch_bounds__(256) void k2_fused(
    const unsigned short* __restrict__ h1cat, // [N1, 256] bf16
    const int*   __restrict__ src1,           // [N2, FANOUT]
    const float* __restrict__ W2,             // [256, NC]
    const float* __restrict__ b2,             // [NC]
    float*       __restrict__ out)            // [N2, NC]
{
    __shared__ float sm[8][256];

    const int tid = threadIdx.x;
    const int r   = tid >> 5;
    const int s   = tid & 31;
    const int row = blockIdx.x * 8 + r;

    float acc[8] = {0.f,0.f,0.f,0.f,0.f,0.f,0.f,0.f};
    #pragma unroll
    for (int j = 0; j < FANOUT; ++j) {
        const int nb = src1[row * FANOUT + j];
        uint4_ v = *(const uint4_*)(h1cat + (size_t)nb * 256 + s * 8);
        acc[0] += bflo(v.x); acc[1] += bfhi(v.x);
        acc[2] += bflo(v.y); acc[3] += bfhi(v.y);
        acc[4] += bflo(v.z); acc[5] += bfhi(v.z);
        acc[6] += bflo(v.w); acc[7] += bfhi(v.w);
    }
    #pragma unroll
    for (int e = 0; e < 8; ++e) sm[r][s * 8 + e] = acc[e] * 0.0625f;
    __syncthreads();

    const int c0 = s, c1 = s + 32;
    float o0 = b2[c0];
    float o1 = (c1 < NC) ? b2[c1] : 0.f;
    for (int k = 0; k < 256; k += 4) {
        f32x4 mv = *(const f32x4*)&sm[r][k];
        #pragma unroll
        for (int e = 0; e < 4; ++e) {
            const float* wrow = W2 + (size_t)(k + e) * NC;
            o0 += mv[e] * wrow[c0];
            if (c1 < NC) o1 += mv[e] * wrow[c1];
        }
    }
    out[(size_t)row * NC + c0] = o0;
    if (c1 < NC) out[(size_t)row * NC + c1] = o1;
}

extern "C" void kernel_launch(void* const* d_in, const int* in_sizes, int n_in,
                              void* d_out, int out_size, void* d_ws, size_t ws_size,
                              hipStream_t stream)
{
    const float* features = (const float*)d_in[0];
    const int*   src0     = (const int*)  d_in[1];
    const int*   src1     = (const int*)  d_in[2];
    const float* W1       = (const float*)d_in[3];
    const float* b1       = (const float*)d_in[4];
    const float* W2       = (const float*)d_in[5];
    const float* b2       = (const float*)d_in[6];
    float*       out      = (float*)d_out;

    unsigned short* Wt    = (unsigned short*)d_ws;        // [NH][K_PAD]  = 128 KB
    unsigned short* H0    = Wt + (size_t)NH * K_PAD;      // [N0][NH] bf16 = 51.2 MB
    unsigned short* h1cat = H0 + (size_t)N0 * NH;         // [N1][256] bf16 = 12.8 MB

    hipLaunchKernelGGL(k0_transpose, dim3(K_PAD / 64), dim3(256), 0, stream, W1, Wt);
    hipLaunchKernelGGL(kA_gemm,   dim3(N0 / ROWS_A), dim3(256), 0, stream, features, Wt, H0);
    hipLaunchKernelGGL(kB_gather, dim3(N1 / 4),      dim3(256), 0, stream, H0, src0, b1, h1cat);
    hipLaunchKernelGGL(k2_fused,  dim3(N2 / 8),      dim3(256), 0, stream, h1cat, src1, W2, b2, out);
}